// Round 1
// 308.667 us; speedup vs baseline: 1.0294x; 1.0294x over previous
//
#include <hip/hip_runtime.h>
#include <math.h>

// B=8, L=2048, D=512, fp32 in/out. bf16 MFMA GEMMs. Column-softmax
// (axis=1 = query axis i): colsum[j]=sum_i exp(S[i,j]); j is the PV
// contraction index, so out = exp(S) @ (vp / colsum[:,None]).
// No max-subtraction needed: |S| <= ~30 with these input scales.

#define TKK 32

typedef __attribute__((ext_vector_type(8))) short bf16x8;
typedef __attribute__((ext_vector_type(4))) float floatx4;

typedef __attribute__((address_space(3))) short lds_short;
typedef const __attribute__((address_space(1))) short glob_short;

__device__ __forceinline__ short f2bf(float x) {
    unsigned u = __float_as_uint(x);
    u += 0x7fff + ((u >> 16) & 1);   // round-to-nearest-even
    return (short)(u >> 16);
}
__device__ __forceinline__ float bf2f(short s) {
    return __uint_as_float(((unsigned)(unsigned short)s) << 16);
}

// ---- fused prep: cast q/k/v (3*4096 blocks), cast W's (3*128), zero colsum (64)
__global__ __launch_bounds__(256) void prep(
    const float* __restrict__ q, const float* __restrict__ k,
    const float* __restrict__ v,
    const float* __restrict__ Wq, const float* __restrict__ Wk,
    const float* __restrict__ Wv,
    short* __restrict__ q_bf, short* __restrict__ k_bf, short* __restrict__ v_bf,
    short* __restrict__ Wq_bf, short* __restrict__ Wk_bf, short* __restrict__ Wv_bf,
    float* __restrict__ colsum)
{
    const int b = blockIdx.x;
    const float* in = nullptr;
    short* out = nullptr;
    long long i;
    if (b < 12288) {
        const int z = b >> 12;
        in  = (z == 0) ? q    : (z == 1) ? k    : v;
        out = (z == 0) ? q_bf : (z == 1) ? k_bf : v_bf;
        i = ((long long)(b & 4095) * 256 + threadIdx.x) * 8;
    } else if (b < 12672) {
        const int z = (b - 12288) >> 7;
        in  = (z == 0) ? Wq    : (z == 1) ? Wk    : Wv;
        out = (z == 0) ? Wq_bf : (z == 1) ? Wk_bf : Wv_bf;
        i = ((long long)((b - 12288) & 127) * 256 + threadIdx.x) * 8;
    } else {
        colsum[(b - 12672) * 256 + threadIdx.x] = 0.f;
        return;
    }
    float4 x = *(const float4*)(in + i);
    float4 y = *(const float4*)(in + i + 4);
    bf16x8 r;
    r[0] = f2bf(x.x); r[1] = f2bf(x.y); r[2] = f2bf(x.z); r[3] = f2bf(x.w);
    r[4] = f2bf(y.x); r[5] = f2bf(y.y); r[6] = f2bf(y.z); r[7] = f2bf(y.w);
    *(bf16x8*)(out + i) = r;
}

// ---------------- generic NT MFMA gemm body ----------------
// C[m,n] = sum_k A[m,k]*B[n,k] (+bias[n]); A:[M][K], B:[N][K] bf16.
template<int TMp, int TNp, int WM, int WN, int HAS_BIAS, int OUT_BF16>
__device__ __forceinline__ void gemm_body(
    const short* __restrict__ A, const short* __restrict__ B,
    const float* __restrict__ bias, void* __restrict__ C,
    int N, int K, int m0, int n0)
{
    __shared__ short As[TMp * TKK];
    __shared__ short Bs[TNp * TKK];
    constexpr int MI = TMp / (16 * WM);
    constexpr int NJ = TNp / (16 * WN);
    const int t    = threadIdx.x;
    const int wave = t >> 6;
    const int lane = t & 63;
    const int wm = (wave / WN) * (TMp / WM);
    const int wn = (wave % WN) * (TNp / WN);
    const int sr = lane >> 2;
    const int sc = (lane & 3) * 8;

    floatx4 acc[MI][NJ];
    #pragma unroll
    for (int i = 0; i < MI; ++i)
        #pragma unroll
        for (int j = 0; j < NJ; ++j)
            acc[i][j] = (floatx4){0.f, 0.f, 0.f, 0.f};

    for (int k0 = 0; k0 < K; k0 += TKK) {
        #pragma unroll
        for (int c = wave; c < TMp / 16; c += 4)
            __builtin_amdgcn_global_load_lds(
                (glob_short*)(A + (long long)(m0 + c * 16 + sr) * K + k0 + sc),
                (lds_short*)(As + c * 512), 16, 0, 0);
        #pragma unroll
        for (int c = wave; c < TNp / 16; c += 4)
            __builtin_amdgcn_global_load_lds(
                (glob_short*)(B + (long long)(n0 + c * 16 + sr) * K + k0 + sc),
                (lds_short*)(Bs + c * 512), 16, 0, 0);
        __syncthreads();
        bf16x8 af[MI], bfr[NJ];
        #pragma unroll
        for (int i = 0; i < MI; ++i)
            af[i] = *(const bf16x8*)&As[(wm + i * 16 + (lane & 15)) * TKK + (lane >> 4) * 8];
        #pragma unroll
        for (int j = 0; j < NJ; ++j)
            bfr[j] = *(const bf16x8*)&Bs[(wn + j * 16 + (lane & 15)) * TKK + (lane >> 4) * 8];
        #pragma unroll
        for (int i = 0; i < MI; ++i)
            #pragma unroll
            for (int j = 0; j < NJ; ++j)
                acc[i][j] = __builtin_amdgcn_mfma_f32_16x16x32_bf16(af[i], bfr[j], acc[i][j], 0, 0, 0);
        __syncthreads();
    }

    // Epilogue: C/D layout col=lane&15, row=(lane>>4)*4+reg (m89-verified)
    #pragma unroll
    for (int i = 0; i < MI; ++i) {
        const int rbase = m0 + wm + i * 16 + (lane >> 4) * 4;
        #pragma unroll
        for (int j = 0; j < NJ; ++j) {
            const int col = n0 + wn + j * 16 + (lane & 15);
            const float bb = HAS_BIAS ? bias[col] : 0.f;
            #pragma unroll
            for (int r = 0; r < 4; ++r) {
                const long long off = (long long)(rbase + r) * N + col;
                const float vvv = acc[i][j][r] + bb;
                if (OUT_BF16) ((short*)C)[off] = f2bf(vvv);
                else          ((float*)C)[off] = vvv;
            }
        }
    }
}

// ---- fused projections: z in {0,1,2} selects (x, W, bias, out) ----
__global__ __launch_bounds__(256) void proj_gemm(
    const short* __restrict__ x0, const short* __restrict__ x1, const short* __restrict__ x2,
    const short* __restrict__ w0, const short* __restrict__ w1, const short* __restrict__ w2,
    const float* __restrict__ b0, const float* __restrict__ b1, const float* __restrict__ b2,
    short* __restrict__ y0, short* __restrict__ y1, short* __restrict__ y2,
    int N, int K)
{
    const int z = blockIdx.z;
    const short* A    = (z == 0) ? x0 : (z == 1) ? x1 : x2;
    const short* B    = (z == 0) ? w0 : (z == 1) ? w1 : w2;
    const float* bias = (z == 0) ? b0 : (z == 1) ? b1 : b2;
    short*       C    = (z == 0) ? y0 : (z == 1) ? y1 : y2;
    gemm_body<128, 128, 2, 2, 1, 1>(A, B, bias, C, N, K,
                                    blockIdx.x * 128, blockIdx.y * 128);
}

// ---- PV gemm: out = E @ vpT^T ----
// R0 change: 64x64 tile -> 128x64 tile, 2 K-blocks per barrier round.
// Theory: pv was latency-bound (MfmaUtil 20%, HBM 25%, nothing saturated);
// 128-wide M doubles MFMA work per staged A-byte (32 -> 42.7 FLOP/B overall,
// 16 MFMA/wave per barrier round) while grid 16x8x8=1024 keeps 4 wg/CU.
__global__ __launch_bounds__(256) void pv_gemm(
    const short* __restrict__ Eg, const short* __restrict__ vpTg,
    float* __restrict__ outg, int N, int K,
    long long sA, long long sB, long long sC)
{
    __shared__ short As[2][128 * TKK];
    __shared__ short Bs[2][64 * TKK];
    const int bz = blockIdx.z;
    const short* A = Eg   + (long long)bz * sA;
    const short* B = vpTg + (long long)bz * sB;
    float*       C = outg + (long long)bz * sC;

    const int m0 = blockIdx.x * 128;
    const int n0 = blockIdx.y * 64;
    const int t    = threadIdx.x;
    const int wave = t >> 6;
    const int lane = t & 63;
    const int wm = (wave >> 1) * 64;   // waves 2x2: 64-row halves
    const int wn = (wave & 1)  * 32;   // 32-col halves
    const int sr = lane >> 2;
    const int sc = (lane & 3) * 8;

    floatx4 acc[4][2];
    #pragma unroll
    for (int i = 0; i < 4; ++i)
        #pragma unroll
        for (int j = 0; j < 2; ++j)
            acc[i][j] = (floatx4){0.f, 0.f, 0.f, 0.f};

    for (int k0 = 0; k0 < K; k0 += 2 * TKK) {
        #pragma unroll
        for (int h = 0; h < 2; ++h) {
            const int kk = k0 + h * TKK;
            // A: 8 chunks of 16 rows, 2 per wave; B: 4 chunks, 1 per wave
            #pragma unroll
            for (int c = wave; c < 8; c += 4)
                __builtin_amdgcn_global_load_lds(
                    (glob_short*)(A + (long long)(m0 + c * 16 + sr) * K + kk + sc),
                    (lds_short*)(As[h] + c * 512), 16, 0, 0);
            __builtin_amdgcn_global_load_lds(
                (glob_short*)(B + (long long)(n0 + wave * 16 + sr) * K + kk + sc),
                (lds_short*)(Bs[h] + wave * 512), 16, 0, 0);
        }
        __syncthreads();
        #pragma unroll
        for (int h = 0; h < 2; ++h) {
            bf16x8 af[4], bfr[2];
            #pragma unroll
            for (int i = 0; i < 4; ++i)
                af[i] = *(const bf16x8*)&As[h][(wm + i * 16 + (lane & 15)) * TKK + (lane >> 4) * 8];
            #pragma unroll
            for (int j = 0; j < 2; ++j)
                bfr[j] = *(const bf16x8*)&Bs[h][(wn + j * 16 + (lane & 15)) * TKK + (lane >> 4) * 8];
            #pragma unroll
            for (int i = 0; i < 4; ++i)
                #pragma unroll
                for (int j = 0; j < 2; ++j)
                    acc[i][j] = __builtin_amdgcn_mfma_f32_16x16x32_bf16(af[i], bfr[j], acc[i][j], 0, 0, 0);
        }
        __syncthreads();
    }

    #pragma unroll
    for (int i = 0; i < 4; ++i) {
        const int rbase = m0 + wm + i * 16 + (lane >> 4) * 4;
        #pragma unroll
        for (int j = 0; j < 2; ++j) {
            const int col = n0 + wn + j * 16 + (lane & 15);
            #pragma unroll
            for (int r = 0; r < 4; ++r)
                C[(long long)(rbase + r) * N + col] = acc[i][j][r];
        }
    }
}

// ---- NT MFMA gemm with fused exp + column-sum: E = exp(A@B^T) bf16,
//      colsum[n] += sum_m exp(...)   (128x128 tile, waves 2x2)
__global__ __launch_bounds__(256) void gemm_nt_exp_colsum(
    const short* __restrict__ A, const short* __restrict__ B,
    short* __restrict__ E, float* __restrict__ colsum,
    int N, int K, long long sA, long long sB, long long sE)
{
    __shared__ short As[128 * TKK];
    __shared__ short Bs[128 * TKK];
    __shared__ float wsum[4][64];
    const int bz = blockIdx.z;
    A += (long long)bz * sA;
    B += (long long)bz * sB;
    E += (long long)bz * sE;
    colsum += (long long)bz * N;

    const int m0 = blockIdx.x * 128;
    const int n0 = blockIdx.y * 128;
    const int t    = threadIdx.x;
    const int wave = t >> 6;
    const int lane = t & 63;
    const int wm = (wave >> 1) * 64;
    const int wn = (wave & 1)  * 64;
    const int sr = lane >> 2;
    const int sc = (lane & 3) * 8;

    floatx4 acc[4][4];
    #pragma unroll
    for (int i = 0; i < 4; ++i)
        #pragma unroll
        for (int j = 0; j < 4; ++j)
            acc[i][j] = (floatx4){0.f, 0.f, 0.f, 0.f};

    for (int k0 = 0; k0 < K; k0 += TKK) {
        #pragma unroll
        for (int it = 0; it < 2; ++it) {
            const int chunk = it * 4 + wave;
            const int r = chunk * 16 + sr;
            __builtin_amdgcn_global_load_lds(
                (glob_short*)(A + (long long)(m0 + r) * K + k0 + sc),
                (lds_short*)(As + chunk * 512), 16, 0, 0);
            __builtin_amdgcn_global_load_lds(
                (glob_short*)(B + (long long)(n0 + r) * K + k0 + sc),
                (lds_short*)(Bs + chunk * 512), 16, 0, 0);
        }
        __syncthreads();
        bf16x8 af[4], bfr[4];
        #pragma unroll
        for (int i = 0; i < 4; ++i)
            af[i] = *(const bf16x8*)&As[(wm + i * 16 + (lane & 15)) * TKK + (lane >> 4) * 8];
        #pragma unroll
        for (int j = 0; j < 4; ++j)
            bfr[j] = *(const bf16x8*)&Bs[(wn + j * 16 + (lane & 15)) * TKK + (lane >> 4) * 8];
        #pragma unroll
        for (int i = 0; i < 4; ++i)
            #pragma unroll
            for (int j = 0; j < 4; ++j)
                acc[i][j] = __builtin_amdgcn_mfma_f32_16x16x32_bf16(af[i], bfr[j], acc[i][j], 0, 0, 0);
        __syncthreads();
    }

    float csum[4] = {0.f, 0.f, 0.f, 0.f};
    #pragma unroll
    for (int i = 0; i < 4; ++i) {
        const int rbase = wm + i * 16 + (lane >> 4) * 4;
        #pragma unroll
        for (int j = 0; j < 4; ++j) {
            const int col = wn + j * 16 + (lane & 15);
            #pragma unroll
            for (int r = 0; r < 4; ++r) {
                const float e = __expf(acc[i][j][r]);
                E[(long long)(m0 + rbase + r) * N + (n0 + col)] = f2bf(e);
                csum[j] += e;
            }
        }
    }
    #pragma unroll
    for (int j = 0; j < 4; ++j) {
        csum[j] += __shfl_xor(csum[j], 16);
        csum[j] += __shfl_xor(csum[j], 32);
    }
    if (lane < 16) {
        #pragma unroll
        for (int j = 0; j < 4; ++j)
            wsum[wave][j * 16 + lane] = csum[j];
    }
    __syncthreads();
    if (t < 128) {
        const float s = (t < 64) ? (wsum[0][t] + wsum[2][t])
                                 : (wsum[1][t - 64] + wsum[3][t - 64]);
        atomicAdd(&colsum[n0 + t], s);
    }
}

// ---- bf16 transpose + per-row scale: out[c][r] = in[r][c] / colsum[r] ----
__global__ __launch_bounds__(256) void transpose_scale_bf16(
    const short* __restrict__ in, const float* __restrict__ colsum,
    short* __restrict__ out, int R, int Cc)
{
    __shared__ short tile[32][33];
    const int b = blockIdx.z;
    in  += (long long)b * R * Cc;
    out += (long long)b * R * Cc;
    colsum += (long long)b * R;
    const int c0 = blockIdx.x * 32, r0 = blockIdx.y * 32;
    const int tx = threadIdx.x & 31, ty = threadIdx.x >> 5;
    #pragma unroll
    for (int rr = ty; rr < 32; rr += 8) {
        const float rs = 1.f / colsum[r0 + rr];
        tile[rr][tx] = f2bf(bf2f(in[(long long)(r0 + rr) * Cc + c0 + tx]) * rs);
    }
    __syncthreads();
    #pragma unroll
    for (int rr = ty; rr < 32; rr += 8)
        out[(long long)(c0 + rr) * R + r0 + tx] = tile[tx][rr];
}

extern "C" void kernel_launch(void* const* d_in, const int* in_sizes, int n_in,
                              void* d_out, int out_size, void* d_ws, size_t ws_size,
                              hipStream_t stream) {
    const float* q  = (const float*)d_in[0];
    const float* k  = (const float*)d_in[1];
    const float* v  = (const float*)d_in[2];
    const float* Wq = (const float*)d_in[3];
    const float* bq = (const float*)d_in[4];
    const float* Wk = (const float*)d_in[5];
    const float* bk = (const float*)d_in[6];
    const float* Wv = (const float*)d_in[7];
    const float* bv = (const float*)d_in[8];
    float* out = (float*)d_out;

    const int Bb = 8, L = 2048, D = 512;
    const long long BLD = (long long)Bb * L * D;   // 8,388,608
    const long long BLL = (long long)Bb * L * L;   // 33,554,432
    const long long DD  = (long long)D * D;

    // ---- workspace layout (shorts unless noted) ----
    short* base  = (short*)d_ws;
    short* q_bf  = base;                 // BLD
    short* k_bf  = q_bf  + BLD;         // BLD
    short* v_bf  = k_bf  + BLD;         // BLD
    short* qp_bf = v_bf  + BLD;         // BLD
    short* kp_bf = qp_bf + BLD;         // BLD
    short* vp_bf = kp_bf + BLD;         // BLD
    short* vpT   = vp_bf + BLD;         // BLD
    short* Wq_bf = vpT   + BLD;         // DD
    short* Wk_bf = Wq_bf + DD;          // DD
    short* Wv_bf = Wk_bf + DD;          // DD
    short* E_bf  = Wv_bf + DD;          // BLL shorts
    float* colsum = (float*)(E_bf + BLL); // B*L floats

    dim3 blk(256);

    // 1) fused casts + colsum zero (12736 blocks)
    prep<<<dim3(12736), blk, 0, stream>>>(q, k, v, Wq, Wk, Wv,
                                          q_bf, k_bf, v_bf,
                                          Wq_bf, Wk_bf, Wv_bf, colsum);

    // 2) fused projections: M=B*L=16384, N=D=512, K=D=512, out bf16
    dim3 gproj((Bb * L) / 128, D / 128, 3);
    proj_gemm<<<gproj, blk, 0, stream>>>(q_bf, k_bf, v_bf,
                                         Wq_bf, Wk_bf, Wv_bf,
                                         bq, bk, bv,
                                         qp_bf, kp_bf, vp_bf, D, D);

    // 3) E = exp(qp @ kp^T), colsum[b,j] = sum_i E[b,i,j]   (M=N=L, K=D)
    dim3 gS(L / 128, L / 128, Bb);
    gemm_nt_exp_colsum<<<gS, blk, 0, stream>>>(qp_bf, kp_bf, E_bf, colsum,
                                               L, D,
                                               (long long)L * D, (long long)L * D,
                                               (long long)L * L);

    // 4) vpT[d][j] = vp[j][d] / colsum[j]  per batch
    dim3 gT(D / 32, L / 32, Bb);
    transpose_scale_bf16<<<gT, blk, 0, stream>>>(vp_bf, colsum, vpT, L, D);

    // 5) out = E @ vpT^T : M=L (128-tiles), N=D (64-tiles), K=L
    dim3 gO(L / 128, D / 64, Bb);
    pv_gemm<<<gO, blk, 0, stream>>>(E_bf, vpT, out, D, L,
                                    (long long)L * L, (long long)D * L,
                                    (long long)L * D);
}

// Round 3
// 304.996 us; speedup vs baseline: 1.0418x; 1.0120x over previous
//
#include <hip/hip_runtime.h>
#include <math.h>

// B=8, L=2048, D=512, fp32 in/out. bf16 MFMA GEMMs. Column-softmax
// (axis=1 = query axis i): colsum[j]=sum_i exp(S[i,j]); j is the PV
// contraction index, so out = exp(S) @ (vp / colsum[:,None]).
// No max-subtraction needed: |S| <= ~30 with these input scales.
// R1: qp is pre-scaled by log2(e) at the projection epilogue, so the
// softmax kernel uses exp2 (v_exp_f32) directly: 1 transcendental, no mul.
// R2: exp2 via inline asm v_exp_f32 (avoids builtin-availability risk).

#define TKK 32

typedef __attribute__((ext_vector_type(8))) short bf16x8;
typedef __attribute__((ext_vector_type(4))) float floatx4;

typedef __attribute__((address_space(3))) short lds_short;
typedef const __attribute__((address_space(1))) short glob_short;

__device__ __forceinline__ short f2bf(float x) {
    unsigned u = __float_as_uint(x);
    u += 0x7fff + ((u >> 16) & 1);   // round-to-nearest-even
    return (short)(u >> 16);
}
__device__ __forceinline__ float bf2f(short s) {
    return __uint_as_float(((unsigned)(unsigned short)s) << 16);
}
__device__ __forceinline__ float exp2_fast(float x) {
    float r;
    asm("v_exp_f32 %0, %1" : "=v"(r) : "v"(x));
    return r;
}

// ---- fused prep: cast q/k/v (3*4096 blocks), cast W's (3*128), zero colsum (64)
__global__ __launch_bounds__(256) void prep(
    const float* __restrict__ q, const float* __restrict__ k,
    const float* __restrict__ v,
    const float* __restrict__ Wq, const float* __restrict__ Wk,
    const float* __restrict__ Wv,
    short* __restrict__ q_bf, short* __restrict__ k_bf, short* __restrict__ v_bf,
    short* __restrict__ Wq_bf, short* __restrict__ Wk_bf, short* __restrict__ Wv_bf,
    float* __restrict__ colsum)
{
    const int b = blockIdx.x;
    const float* in = nullptr;
    short* out = nullptr;
    long long i;
    if (b < 12288) {
        const int z = b >> 12;
        in  = (z == 0) ? q    : (z == 1) ? k    : v;
        out = (z == 0) ? q_bf : (z == 1) ? k_bf : v_bf;
        i = ((long long)(b & 4095) * 256 + threadIdx.x) * 8;
    } else if (b < 12672) {
        const int z = (b - 12288) >> 7;
        in  = (z == 0) ? Wq    : (z == 1) ? Wk    : Wv;
        out = (z == 0) ? Wq_bf : (z == 1) ? Wk_bf : Wv_bf;
        i = ((long long)((b - 12288) & 127) * 256 + threadIdx.x) * 8;
    } else {
        colsum[(b - 12672) * 256 + threadIdx.x] = 0.f;
        return;
    }
    float4 x = *(const float4*)(in + i);
    float4 y = *(const float4*)(in + i + 4);
    bf16x8 r;
    r[0] = f2bf(x.x); r[1] = f2bf(x.y); r[2] = f2bf(x.z); r[3] = f2bf(x.w);
    r[4] = f2bf(y.x); r[5] = f2bf(y.y); r[6] = f2bf(y.z); r[7] = f2bf(y.w);
    *(bf16x8*)(out + i) = r;
}

// ---------------- generic NT MFMA gemm body ----------------
// C[m,n] = (sum_k A[m,k]*B[n,k] + bias[n]) * escale; A:[M][K], B:[N][K] bf16.
template<int TMp, int TNp, int WM, int WN, int HAS_BIAS, int OUT_BF16>
__device__ __forceinline__ void gemm_body(
    const short* __restrict__ A, const short* __restrict__ B,
    const float* __restrict__ bias, void* __restrict__ C,
    int N, int K, int m0, int n0, float escale)
{
    __shared__ short As[TMp * TKK];
    __shared__ short Bs[TNp * TKK];
    constexpr int MI = TMp / (16 * WM);
    constexpr int NJ = TNp / (16 * WN);
    const int t    = threadIdx.x;
    const int wave = t >> 6;
    const int lane = t & 63;
    const int wm = (wave / WN) * (TMp / WM);
    const int wn = (wave % WN) * (TNp / WN);
    const int sr = lane >> 2;
    const int sc = (lane & 3) * 8;

    floatx4 acc[MI][NJ];
    #pragma unroll
    for (int i = 0; i < MI; ++i)
        #pragma unroll
        for (int j = 0; j < NJ; ++j)
            acc[i][j] = (floatx4){0.f, 0.f, 0.f, 0.f};

    for (int k0 = 0; k0 < K; k0 += TKK) {
        #pragma unroll
        for (int c = wave; c < TMp / 16; c += 4)
            __builtin_amdgcn_global_load_lds(
                (glob_short*)(A + (long long)(m0 + c * 16 + sr) * K + k0 + sc),
                (lds_short*)(As + c * 512), 16, 0, 0);
        #pragma unroll
        for (int c = wave; c < TNp / 16; c += 4)
            __builtin_amdgcn_global_load_lds(
                (glob_short*)(B + (long long)(n0 + c * 16 + sr) * K + k0 + sc),
                (lds_short*)(Bs + c * 512), 16, 0, 0);
        __syncthreads();
        bf16x8 af[MI], bfr[NJ];
        #pragma unroll
        for (int i = 0; i < MI; ++i)
            af[i] = *(const bf16x8*)&As[(wm + i * 16 + (lane & 15)) * TKK + (lane >> 4) * 8];
        #pragma unroll
        for (int j = 0; j < NJ; ++j)
            bfr[j] = *(const bf16x8*)&Bs[(wn + j * 16 + (lane & 15)) * TKK + (lane >> 4) * 8];
        #pragma unroll
        for (int i = 0; i < MI; ++i)
            #pragma unroll
            for (int j = 0; j < NJ; ++j)
                acc[i][j] = __builtin_amdgcn_mfma_f32_16x16x32_bf16(af[i], bfr[j], acc[i][j], 0, 0, 0);
        __syncthreads();
    }

    // Epilogue: C/D layout col=lane&15, row=(lane>>4)*4+reg (m89-verified)
    #pragma unroll
    for (int i = 0; i < MI; ++i) {
        const int rbase = m0 + wm + i * 16 + (lane >> 4) * 4;
        #pragma unroll
        for (int j = 0; j < NJ; ++j) {
            const int col = n0 + wn + j * 16 + (lane & 15);
            const float bb = HAS_BIAS ? bias[col] : 0.f;
            #pragma unroll
            for (int r = 0; r < 4; ++r) {
                const long long off = (long long)(rbase + r) * N + col;
                const float vvv = (acc[i][j][r] + bb) * escale;
                if (OUT_BF16) ((short*)C)[off] = f2bf(vvv);
                else          ((float*)C)[off] = vvv;
            }
        }
    }
}

// ---- fused projections: z in {0,1,2} selects (x, W, bias, out) ----
// z==0 (qp) is scaled by log2(e) so the S kernel can use exp2 directly.
__global__ __launch_bounds__(256) void proj_gemm(
    const short* __restrict__ x0, const short* __restrict__ x1, const short* __restrict__ x2,
    const short* __restrict__ w0, const short* __restrict__ w1, const short* __restrict__ w2,
    const float* __restrict__ b0, const float* __restrict__ b1, const float* __restrict__ b2,
    short* __restrict__ y0, short* __restrict__ y1, short* __restrict__ y2,
    int N, int K)
{
    const int z = blockIdx.z;
    const short* A    = (z == 0) ? x0 : (z == 1) ? x1 : x2;
    const short* B    = (z == 0) ? w0 : (z == 1) ? w1 : w2;
    const float* bias = (z == 0) ? b0 : (z == 1) ? b1 : b2;
    short*       C    = (z == 0) ? y0 : (z == 1) ? y1 : y2;
    const float esc   = (z == 0) ? 1.4426950408889634f : 1.0f;
    gemm_body<128, 128, 2, 2, 1, 1>(A, B, bias, C, N, K,
                                    blockIdx.x * 128, blockIdx.y * 128, esc);
}

// ---- PV gemm: out = E @ vpT^T ----
// 128x64 tile, 2 K-blocks per barrier round (R0 win: latency-bound fix).
__global__ __launch_bounds__(256) void pv_gemm(
    const short* __restrict__ Eg, const short* __restrict__ vpTg,
    float* __restrict__ outg, int N, int K,
    long long sA, long long sB, long long sC)
{
    __shared__ short As[2][128 * TKK];
    __shared__ short Bs[2][64 * TKK];
    const int bz = blockIdx.z;
    const short* A = Eg   + (long long)bz * sA;
    const short* B = vpTg + (long long)bz * sB;
    float*       C = outg + (long long)bz * sC;

    const int m0 = blockIdx.x * 128;
    const int n0 = blockIdx.y * 64;
    const int t    = threadIdx.x;
    const int wave = t >> 6;
    const int lane = t & 63;
    const int wm = (wave >> 1) * 64;   // waves 2x2: 64-row halves
    const int wn = (wave & 1)  * 32;   // 32-col halves
    const int sr = lane >> 2;
    const int sc = (lane & 3) * 8;

    floatx4 acc[4][2];
    #pragma unroll
    for (int i = 0; i < 4; ++i)
        #pragma unroll
        for (int j = 0; j < 2; ++j)
            acc[i][j] = (floatx4){0.f, 0.f, 0.f, 0.f};

    for (int k0 = 0; k0 < K; k0 += 2 * TKK) {
        #pragma unroll
        for (int h = 0; h < 2; ++h) {
            const int kk = k0 + h * TKK;
            // A: 8 chunks of 16 rows, 2 per wave; B: 4 chunks, 1 per wave
            #pragma unroll
            for (int c = wave; c < 8; c += 4)
                __builtin_amdgcn_global_load_lds(
                    (glob_short*)(A + (long long)(m0 + c * 16 + sr) * K + kk + sc),
                    (lds_short*)(As[h] + c * 512), 16, 0, 0);
            __builtin_amdgcn_global_load_lds(
                (glob_short*)(B + (long long)(n0 + wave * 16 + sr) * K + kk + sc),
                (lds_short*)(Bs[h] + wave * 512), 16, 0, 0);
        }
        __syncthreads();
        #pragma unroll
        for (int h = 0; h < 2; ++h) {
            bf16x8 af[4], bfr[2];
            #pragma unroll
            for (int i = 0; i < 4; ++i)
                af[i] = *(const bf16x8*)&As[h][(wm + i * 16 + (lane & 15)) * TKK + (lane >> 4) * 8];
            #pragma unroll
            for (int j = 0; j < 2; ++j)
                bfr[j] = *(const bf16x8*)&Bs[h][(wn + j * 16 + (lane & 15)) * TKK + (lane >> 4) * 8];
            #pragma unroll
            for (int i = 0; i < 4; ++i)
                #pragma unroll
                for (int j = 0; j < 2; ++j)
                    acc[i][j] = __builtin_amdgcn_mfma_f32_16x16x32_bf16(af[i], bfr[j], acc[i][j], 0, 0, 0);
        }
        __syncthreads();
    }

    #pragma unroll
    for (int i = 0; i < 4; ++i) {
        const int rbase = m0 + wm + i * 16 + (lane >> 4) * 4;
        #pragma unroll
        for (int j = 0; j < 2; ++j) {
            const int col = n0 + wn + j * 16 + (lane & 15);
            #pragma unroll
            for (int r = 0; r < 4; ++r)
                C[(long long)(rbase + r) * N + col] = acc[i][j][r];
        }
    }
}

// ---- NT MFMA gemm with fused exp2 + column-sum: E = exp2(A@B^T) bf16,
//      colsum[n] += sum_m exp2(...)   (128x128 tile, waves 2x2)
// R1: 2 K-blocks per barrier round (16 -> 8 barrier rounds), exp2 epilogue.
__global__ __launch_bounds__(256) void gemm_nt_exp_colsum(
    const short* __restrict__ A, const short* __restrict__ B,
    short* __restrict__ E, float* __restrict__ colsum,
    int N, int K, long long sA, long long sB, long long sE)
{
    __shared__ short As[2][128 * TKK];
    __shared__ short Bs[2][128 * TKK];
    __shared__ float wsum[4][64];
    const int bz = blockIdx.z;
    A += (long long)bz * sA;
    B += (long long)bz * sB;
    E += (long long)bz * sE;
    colsum += (long long)bz * N;

    const int m0 = blockIdx.x * 128;
    const int n0 = blockIdx.y * 128;
    const int t    = threadIdx.x;
    const int wave = t >> 6;
    const int lane = t & 63;
    const int wm = (wave >> 1) * 64;
    const int wn = (wave & 1)  * 64;
    const int sr = lane >> 2;
    const int sc = (lane & 3) * 8;

    floatx4 acc[4][4];
    #pragma unroll
    for (int i = 0; i < 4; ++i)
        #pragma unroll
        for (int j = 0; j < 4; ++j)
            acc[i][j] = (floatx4){0.f, 0.f, 0.f, 0.f};

    for (int k0 = 0; k0 < K; k0 += 2 * TKK) {
        #pragma unroll
        for (int h = 0; h < 2; ++h) {
            const int kk = k0 + h * TKK;
            #pragma unroll
            for (int it = 0; it < 2; ++it) {
                const int chunk = it * 4 + wave;
                const int r = chunk * 16 + sr;
                __builtin_amdgcn_global_load_lds(
                    (glob_short*)(A + (long long)(m0 + r) * K + kk + sc),
                    (lds_short*)(As[h] + chunk * 512), 16, 0, 0);
                __builtin_amdgcn_global_load_lds(
                    (glob_short*)(B + (long long)(n0 + r) * K + kk + sc),
                    (lds_short*)(Bs[h] + chunk * 512), 16, 0, 0);
            }
        }
        __syncthreads();
        #pragma unroll
        for (int h = 0; h < 2; ++h) {
            bf16x8 af[4], bfr[4];
            #pragma unroll
            for (int i = 0; i < 4; ++i)
                af[i] = *(const bf16x8*)&As[h][(wm + i * 16 + (lane & 15)) * TKK + (lane >> 4) * 8];
            #pragma unroll
            for (int j = 0; j < 4; ++j)
                bfr[j] = *(const bf16x8*)&Bs[h][(wn + j * 16 + (lane & 15)) * TKK + (lane >> 4) * 8];
            #pragma unroll
            for (int i = 0; i < 4; ++i)
                #pragma unroll
                for (int j = 0; j < 4; ++j)
                    acc[i][j] = __builtin_amdgcn_mfma_f32_16x16x32_bf16(af[i], bfr[j], acc[i][j], 0, 0, 0);
        }
        __syncthreads();
    }

    float csum[4] = {0.f, 0.f, 0.f, 0.f};
    #pragma unroll
    for (int i = 0; i < 4; ++i) {
        const int rbase = wm + i * 16 + (lane >> 4) * 4;
        #pragma unroll
        for (int j = 0; j < 4; ++j) {
            const int col = wn + j * 16 + (lane & 15);
            #pragma unroll
            for (int r = 0; r < 4; ++r) {
                const float e = exp2_fast(acc[i][j][r]);
                E[(long long)(m0 + rbase + r) * N + (n0 + col)] = f2bf(e);
                csum[j] += e;
            }
        }
    }
    #pragma unroll
    for (int j = 0; j < 4; ++j) {
        csum[j] += __shfl_xor(csum[j], 16);
        csum[j] += __shfl_xor(csum[j], 32);
    }
    if (lane < 16) {
        #pragma unroll
        for (int j = 0; j < 4; ++j)
            wsum[wave][j * 16 + lane] = csum[j];
    }
    __syncthreads();
    if (t < 128) {
        const float s = (t < 64) ? (wsum[0][t] + wsum[2][t])
                                 : (wsum[1][t - 64] + wsum[3][t - 64]);
        atomicAdd(&colsum[n0 + t], s);
    }
}

// ---- bf16 transpose + per-row scale: out[c][r] = in[r][c] / colsum[r] ----
__global__ __launch_bounds__(256) void transpose_scale_bf16(
    const short* __restrict__ in, const float* __restrict__ colsum,
    short* __restrict__ out, int R, int Cc)
{
    __shared__ short tile[32][33];
    const int b = blockIdx.z;
    in  += (long long)b * R * Cc;
    out += (long long)b * R * Cc;
    colsum += (long long)b * R;
    const int c0 = blockIdx.x * 32, r0 = blockIdx.y * 32;
    const int tx = threadIdx.x & 31, ty = threadIdx.x >> 5;
    #pragma unroll
    for (int rr = ty; rr < 32; rr += 8) {
        const float rs = 1.f / colsum[r0 + rr];
        tile[rr][tx] = f2bf(bf2f(in[(long long)(r0 + rr) * Cc + c0 + tx]) * rs);
    }
    __syncthreads();
    #pragma unroll
    for (int rr = ty; rr < 32; rr += 8)
        out[(long long)(c0 + rr) * R + r0 + tx] = tile[tx][rr];
}

extern "C" void kernel_launch(void* const* d_in, const int* in_sizes, int n_in,
                              void* d_out, int out_size, void* d_ws, size_t ws_size,
                              hipStream_t stream) {
    const float* q  = (const float*)d_in[0];
    const float* k  = (const float*)d_in[1];
    const float* v  = (const float*)d_in[2];
    const float* Wq = (const float*)d_in[3];
    const float* bq = (const float*)d_in[4];
    const float* Wk = (const float*)d_in[5];
    const float* bk = (const float*)d_in[6];
    const float* Wv = (const float*)d_in[7];
    const float* bv = (const float*)d_in[8];
    float* out = (float*)d_out;

    const int Bb = 8, L = 2048, D = 512;
    const long long BLD = (long long)Bb * L * D;   // 8,388,608
    const long long BLL = (long long)Bb * L * L;   // 33,554,432
    const long long DD  = (long long)D * D;

    // ---- workspace layout (shorts unless noted) ----
    short* base  = (short*)d_ws;
    short* q_bf  = base;                 // BLD
    short* k_bf  = q_bf  + BLD;         // BLD
    short* v_bf  = k_bf  + BLD;         // BLD
    short* qp_bf = v_bf  + BLD;         // BLD
    short* kp_bf = qp_bf + BLD;         // BLD
    short* vp_bf = kp_bf + BLD;         // BLD
    short* vpT   = vp_bf + BLD;         // BLD
    short* Wq_bf = vpT   + BLD;         // DD
    short* Wk_bf = Wq_bf + DD;          // DD
    short* Wv_bf = Wk_bf + DD;          // DD
    short* E_bf  = Wv_bf + DD;          // BLL shorts
    float* colsum = (float*)(E_bf + BLL); // B*L floats

    dim3 blk(256);

    // 1) fused casts + colsum zero (12736 blocks)
    prep<<<dim3(12736), blk, 0, stream>>>(q, k, v, Wq, Wk, Wv,
                                          q_bf, k_bf, v_bf,
                                          Wq_bf, Wk_bf, Wv_bf, colsum);

    // 2) fused projections: M=B*L=16384, N=D=512, K=D=512, out bf16
    dim3 gproj((Bb * L) / 128, D / 128, 3);
    proj_gemm<<<gproj, blk, 0, stream>>>(q_bf, k_bf, v_bf,
                                         Wq_bf, Wk_bf, Wv_bf,
                                         bq, bk, bv,
                                         qp_bf, kp_bf, vp_bf, D, D);

    // 3) E = exp2(qp @ kp^T), colsum[b,j] = sum_i E[b,i,j]   (M=N=L, K=D)
    dim3 gS(L / 128, L / 128, Bb);
    gemm_nt_exp_colsum<<<gS, blk, 0, stream>>>(qp_bf, kp_bf, E_bf, colsum,
                                               L, D,
                                               (long long)L * D, (long long)L * D,
                                               (long long)L * L);

    // 4) vpT[d][j] = vp[j][d] / colsum[j]  per batch
    dim3 gT(D / 32, L / 32, Bb);
    transpose_scale_bf16<<<gT, blk, 0, stream>>>(vp_bf, colsum, vpT, L, D);

    // 5) out = E @ vpT^T : M=L (128-tiles), N=D (64-tiles), K=L
    dim3 gO(L / 128, D / 64, Bb);
    pv_gemm<<<gO, blk, 0, stream>>>(E_bf, vpT, out, D, L,
                                    (long long)L * L, (long long)D * L,
                                    (long long)L * D);
}

// Round 4
// 298.029 us; speedup vs baseline: 1.0661x; 1.0234x over previous
//
#include <hip/hip_runtime.h>
#include <math.h>

// B=8, L=2048, D=512, fp32 in/out. bf16 MFMA GEMMs. Column-softmax
// (axis=1 = query axis i): colsum[j]=sum_i exp(S[i,j]); j is the PV
// contraction index, so out = exp(S) @ (vp / colsum[:,None]).
// No max-subtraction needed: |S| <= ~30 with these input scales.
// R1: qp pre-scaled by log2(e); softmax kernel uses exp2 (v_exp_f32).
// R3: LDS XOR-swizzle (col16B ^= (row>>1)&3) on all GEMM staging+reads:
//     kills the 8-way bank conflict of the 16-rows-at-one-column fragment
//     read (6.3M conflict cycles on pv). Swizzle applied on the GLOBAL
//     source (global_load_lds dest must stay linear) and on ds_read addr.

#define TKK 32

typedef __attribute__((ext_vector_type(8))) short bf16x8;
typedef __attribute__((ext_vector_type(4))) float floatx4;

typedef __attribute__((address_space(3))) short lds_short;
typedef const __attribute__((address_space(1))) short glob_short;

__device__ __forceinline__ short f2bf(float x) {
    unsigned u = __float_as_uint(x);
    u += 0x7fff + ((u >> 16) & 1);   // round-to-nearest-even
    return (short)(u >> 16);
}
__device__ __forceinline__ float bf2f(short s) {
    return __uint_as_float(((unsigned)(unsigned short)s) << 16);
}
__device__ __forceinline__ float exp2_fast(float x) {
    float r;
    asm("v_exp_f32 %0, %1" : "=v"(r) : "v"(x));
    return r;
}

// Stage-side swizzled column (shorts): global col unit permuted per row so
// that linear LDS rows hold XOR-swizzled data. sr = lane>>2 (row in chunk),
// unit = lane&3; swz = (row>>1)&3 = (lane>>3)&3 (chunk base is mult of 16).
#define STAGE_SC(lane) ((((lane) & 3) ^ (((lane) >> 3) & 3)) * 8)
// Read-side swizzled fragment column (shorts): h = lane>>4, row ≡ lane&15,
// s(row) = ((lane&15)>>1)&3 = (lane>>1)&3.
#define FRAG_FC(lane) (((((lane) >> 4) ^ (((lane) >> 1) & 3))) * 8)

// ---- fused prep: cast q/k/v (3*4096 blocks), cast W's (3*128), zero colsum (64)
__global__ __launch_bounds__(256) void prep(
    const float* __restrict__ q, const float* __restrict__ k,
    const float* __restrict__ v,
    const float* __restrict__ Wq, const float* __restrict__ Wk,
    const float* __restrict__ Wv,
    short* __restrict__ q_bf, short* __restrict__ k_bf, short* __restrict__ v_bf,
    short* __restrict__ Wq_bf, short* __restrict__ Wk_bf, short* __restrict__ Wv_bf,
    float* __restrict__ colsum)
{
    const int b = blockIdx.x;
    const float* in = nullptr;
    short* out = nullptr;
    long long i;
    if (b < 12288) {
        const int z = b >> 12;
        in  = (z == 0) ? q    : (z == 1) ? k    : v;
        out = (z == 0) ? q_bf : (z == 1) ? k_bf : v_bf;
        i = ((long long)(b & 4095) * 256 + threadIdx.x) * 8;
    } else if (b < 12672) {
        const int z = (b - 12288) >> 7;
        in  = (z == 0) ? Wq    : (z == 1) ? Wk    : Wv;
        out = (z == 0) ? Wq_bf : (z == 1) ? Wk_bf : Wv_bf;
        i = ((long long)((b - 12288) & 127) * 256 + threadIdx.x) * 8;
    } else {
        colsum[(b - 12672) * 256 + threadIdx.x] = 0.f;
        return;
    }
    float4 x = *(const float4*)(in + i);
    float4 y = *(const float4*)(in + i + 4);
    bf16x8 r;
    r[0] = f2bf(x.x); r[1] = f2bf(x.y); r[2] = f2bf(x.z); r[3] = f2bf(x.w);
    r[4] = f2bf(y.x); r[5] = f2bf(y.y); r[6] = f2bf(y.z); r[7] = f2bf(y.w);
    *(bf16x8*)(out + i) = r;
}

// ---------------- generic NT MFMA gemm body ----------------
// C[m,n] = (sum_k A[m,k]*B[n,k] + bias[n]) * escale; A:[M][K], B:[N][K] bf16.
template<int TMp, int TNp, int WM, int WN, int HAS_BIAS, int OUT_BF16>
__device__ __forceinline__ void gemm_body(
    const short* __restrict__ A, const short* __restrict__ B,
    const float* __restrict__ bias, void* __restrict__ C,
    int N, int K, int m0, int n0, float escale)
{
    __shared__ short As[TMp * TKK];
    __shared__ short Bs[TNp * TKK];
    constexpr int MI = TMp / (16 * WM);
    constexpr int NJ = TNp / (16 * WN);
    const int t    = threadIdx.x;
    const int wave = t >> 6;
    const int lane = t & 63;
    const int wm = (wave / WN) * (TMp / WM);
    const int wn = (wave % WN) * (TNp / WN);
    const int sr = lane >> 2;
    const int sc = STAGE_SC(lane);
    const int fc = FRAG_FC(lane);

    floatx4 acc[MI][NJ];
    #pragma unroll
    for (int i = 0; i < MI; ++i)
        #pragma unroll
        for (int j = 0; j < NJ; ++j)
            acc[i][j] = (floatx4){0.f, 0.f, 0.f, 0.f};

    for (int k0 = 0; k0 < K; k0 += TKK) {
        #pragma unroll
        for (int c = wave; c < TMp / 16; c += 4)
            __builtin_amdgcn_global_load_lds(
                (glob_short*)(A + (long long)(m0 + c * 16 + sr) * K + k0 + sc),
                (lds_short*)(As + c * 512), 16, 0, 0);
        #pragma unroll
        for (int c = wave; c < TNp / 16; c += 4)
            __builtin_amdgcn_global_load_lds(
                (glob_short*)(B + (long long)(n0 + c * 16 + sr) * K + k0 + sc),
                (lds_short*)(Bs + c * 512), 16, 0, 0);
        __syncthreads();
        bf16x8 af[MI], bfr[NJ];
        #pragma unroll
        for (int i = 0; i < MI; ++i)
            af[i] = *(const bf16x8*)&As[(wm + i * 16 + (lane & 15)) * TKK + fc];
        #pragma unroll
        for (int j = 0; j < NJ; ++j)
            bfr[j] = *(const bf16x8*)&Bs[(wn + j * 16 + (lane & 15)) * TKK + fc];
        #pragma unroll
        for (int i = 0; i < MI; ++i)
            #pragma unroll
            for (int j = 0; j < NJ; ++j)
                acc[i][j] = __builtin_amdgcn_mfma_f32_16x16x32_bf16(af[i], bfr[j], acc[i][j], 0, 0, 0);
        __syncthreads();
    }

    // Epilogue: C/D layout col=lane&15, row=(lane>>4)*4+reg (m89-verified)
    #pragma unroll
    for (int i = 0; i < MI; ++i) {
        const int rbase = m0 + wm + i * 16 + (lane >> 4) * 4;
        #pragma unroll
        for (int j = 0; j < NJ; ++j) {
            const int col = n0 + wn + j * 16 + (lane & 15);
            const float bb = HAS_BIAS ? bias[col] : 0.f;
            #pragma unroll
            for (int r = 0; r < 4; ++r) {
                const long long off = (long long)(rbase + r) * N + col;
                const float vvv = (acc[i][j][r] + bb) * escale;
                if (OUT_BF16) ((short*)C)[off] = f2bf(vvv);
                else          ((float*)C)[off] = vvv;
            }
        }
    }
}

// ---- fused projections: z in {0,1,2} selects (x, W, bias, out) ----
// z==0 (qp) is scaled by log2(e) so the S kernel can use exp2 directly.
__global__ __launch_bounds__(256) void proj_gemm(
    const short* __restrict__ x0, const short* __restrict__ x1, const short* __restrict__ x2,
    const short* __restrict__ w0, const short* __restrict__ w1, const short* __restrict__ w2,
    const float* __restrict__ b0, const float* __restrict__ b1, const float* __restrict__ b2,
    short* __restrict__ y0, short* __restrict__ y1, short* __restrict__ y2,
    int N, int K)
{
    const int z = blockIdx.z;
    const short* A    = (z == 0) ? x0 : (z == 1) ? x1 : x2;
    const short* B    = (z == 0) ? w0 : (z == 1) ? w1 : w2;
    const float* bias = (z == 0) ? b0 : (z == 1) ? b1 : b2;
    short*       C    = (z == 0) ? y0 : (z == 1) ? y1 : y2;
    const float esc   = (z == 0) ? 1.4426950408889634f : 1.0f;
    gemm_body<128, 128, 2, 2, 1, 1>(A, B, bias, C, N, K,
                                    blockIdx.x * 128, blockIdx.y * 128, esc);
}

// ---- PV gemm: out = E @ vpT^T ----
// 128x64 tile, 2 K-blocks per barrier round (R0 win: latency-bound fix).
__global__ __launch_bounds__(256) void pv_gemm(
    const short* __restrict__ Eg, const short* __restrict__ vpTg,
    float* __restrict__ outg, int N, int K,
    long long sA, long long sB, long long sC)
{
    __shared__ short As[2][128 * TKK];
    __shared__ short Bs[2][64 * TKK];
    const int bz = blockIdx.z;
    const short* A = Eg   + (long long)bz * sA;
    const short* B = vpTg + (long long)bz * sB;
    float*       C = outg + (long long)bz * sC;

    const int m0 = blockIdx.x * 128;
    const int n0 = blockIdx.y * 64;
    const int t    = threadIdx.x;
    const int wave = t >> 6;
    const int lane = t & 63;
    const int wm = (wave >> 1) * 64;   // waves 2x2: 64-row halves
    const int wn = (wave & 1)  * 32;   // 32-col halves
    const int sr = lane >> 2;
    const int sc = STAGE_SC(lane);
    const int fc = FRAG_FC(lane);

    floatx4 acc[4][2];
    #pragma unroll
    for (int i = 0; i < 4; ++i)
        #pragma unroll
        for (int j = 0; j < 2; ++j)
            acc[i][j] = (floatx4){0.f, 0.f, 0.f, 0.f};

    for (int k0 = 0; k0 < K; k0 += 2 * TKK) {
        #pragma unroll
        for (int h = 0; h < 2; ++h) {
            const int kk = k0 + h * TKK;
            // A: 8 chunks of 16 rows, 2 per wave; B: 4 chunks, 1 per wave
            #pragma unroll
            for (int c = wave; c < 8; c += 4)
                __builtin_amdgcn_global_load_lds(
                    (glob_short*)(A + (long long)(m0 + c * 16 + sr) * K + kk + sc),
                    (lds_short*)(As[h] + c * 512), 16, 0, 0);
            __builtin_amdgcn_global_load_lds(
                (glob_short*)(B + (long long)(n0 + wave * 16 + sr) * K + kk + sc),
                (lds_short*)(Bs[h] + wave * 512), 16, 0, 0);
        }
        __syncthreads();
        #pragma unroll
        for (int h = 0; h < 2; ++h) {
            bf16x8 af[4], bfr[2];
            #pragma unroll
            for (int i = 0; i < 4; ++i)
                af[i] = *(const bf16x8*)&As[h][(wm + i * 16 + (lane & 15)) * TKK + fc];
            #pragma unroll
            for (int j = 0; j < 2; ++j)
                bfr[j] = *(const bf16x8*)&Bs[h][(wn + j * 16 + (lane & 15)) * TKK + fc];
            #pragma unroll
            for (int i = 0; i < 4; ++i)
                #pragma unroll
                for (int j = 0; j < 2; ++j)
                    acc[i][j] = __builtin_amdgcn_mfma_f32_16x16x32_bf16(af[i], bfr[j], acc[i][j], 0, 0, 0);
        }
        __syncthreads();
    }

    #pragma unroll
    for (int i = 0; i < 4; ++i) {
        const int rbase = m0 + wm + i * 16 + (lane >> 4) * 4;
        #pragma unroll
        for (int j = 0; j < 2; ++j) {
            const int col = n0 + wn + j * 16 + (lane & 15);
            #pragma unroll
            for (int r = 0; r < 4; ++r)
                C[(long long)(rbase + r) * N + col] = acc[i][j][r];
        }
    }
}

// ---- NT MFMA gemm with fused exp2 + column-sum: E = exp2(A@B^T) bf16,
//      colsum[n] += sum_m exp2(...)   (128x128 tile, waves 2x2)
// R1: 2 K-blocks per barrier round (16 -> 8 barrier rounds), exp2 epilogue.
__global__ __launch_bounds__(256) void gemm_nt_exp_colsum(
    const short* __restrict__ A, const short* __restrict__ B,
    short* __restrict__ E, float* __restrict__ colsum,
    int N, int K, long long sA, long long sB, long long sE)
{
    __shared__ short As[2][128 * TKK];
    __shared__ short Bs[2][128 * TKK];
    __shared__ float wsum[4][64];
    const int bz = blockIdx.z;
    A += (long long)bz * sA;
    B += (long long)bz * sB;
    E += (long long)bz * sE;
    colsum += (long long)bz * N;

    const int m0 = blockIdx.x * 128;
    const int n0 = blockIdx.y * 128;
    const int t    = threadIdx.x;
    const int wave = t >> 6;
    const int lane = t & 63;
    const int wm = (wave >> 1) * 64;
    const int wn = (wave & 1)  * 64;
    const int sr = lane >> 2;
    const int sc = STAGE_SC(lane);
    const int fc = FRAG_FC(lane);

    floatx4 acc[4][4];
    #pragma unroll
    for (int i = 0; i < 4; ++i)
        #pragma unroll
        for (int j = 0; j < 4; ++j)
            acc[i][j] = (floatx4){0.f, 0.f, 0.f, 0.f};

    for (int k0 = 0; k0 < K; k0 += 2 * TKK) {
        #pragma unroll
        for (int h = 0; h < 2; ++h) {
            const int kk = k0 + h * TKK;
            #pragma unroll
            for (int it = 0; it < 2; ++it) {
                const int chunk = it * 4 + wave;
                const int r = chunk * 16 + sr;
                __builtin_amdgcn_global_load_lds(
                    (glob_short*)(A + (long long)(m0 + r) * K + kk + sc),
                    (lds_short*)(As[h] + chunk * 512), 16, 0, 0);
                __builtin_amdgcn_global_load_lds(
                    (glob_short*)(B + (long long)(n0 + r) * K + kk + sc),
                    (lds_short*)(Bs[h] + chunk * 512), 16, 0, 0);
            }
        }
        __syncthreads();
        #pragma unroll
        for (int h = 0; h < 2; ++h) {
            bf16x8 af[4], bfr[4];
            #pragma unroll
            for (int i = 0; i < 4; ++i)
                af[i] = *(const bf16x8*)&As[h][(wm + i * 16 + (lane & 15)) * TKK + fc];
            #pragma unroll
            for (int j = 0; j < 4; ++j)
                bfr[j] = *(const bf16x8*)&Bs[h][(wn + j * 16 + (lane & 15)) * TKK + fc];
            #pragma unroll
            for (int i = 0; i < 4; ++i)
                #pragma unroll
                for (int j = 0; j < 4; ++j)
                    acc[i][j] = __builtin_amdgcn_mfma_f32_16x16x32_bf16(af[i], bfr[j], acc[i][j], 0, 0, 0);
        }
        __syncthreads();
    }

    float csum[4] = {0.f, 0.f, 0.f, 0.f};
    #pragma unroll
    for (int i = 0; i < 4; ++i) {
        const int rbase = wm + i * 16 + (lane >> 4) * 4;
        #pragma unroll
        for (int j = 0; j < 4; ++j) {
            const int col = wn + j * 16 + (lane & 15);
            #pragma unroll
            for (int r = 0; r < 4; ++r) {
                const float e = exp2_fast(acc[i][j][r]);
                E[(long long)(m0 + rbase + r) * N + (n0 + col)] = f2bf(e);
                csum[j] += e;
            }
        }
    }
    #pragma unroll
    for (int j = 0; j < 4; ++j) {
        csum[j] += __shfl_xor(csum[j], 16);
        csum[j] += __shfl_xor(csum[j], 32);
    }
    if (lane < 16) {
        #pragma unroll
        for (int j = 0; j < 4; ++j)
            wsum[wave][j * 16 + lane] = csum[j];
    }
    __syncthreads();
    if (t < 128) {
        const float s = (t < 64) ? (wsum[0][t] + wsum[2][t])
                                 : (wsum[1][t - 64] + wsum[3][t - 64]);
        atomicAdd(&colsum[n0 + t], s);
    }
}

// ---- bf16 transpose + per-row scale: out[c][r] = in[r][c] / colsum[r] ----
__global__ __launch_bounds__(256) void transpose_scale_bf16(
    const short* __restrict__ in, const float* __restrict__ colsum,
    short* __restrict__ out, int R, int Cc)
{
    __shared__ short tile[32][33];
    const int b = blockIdx.z;
    in  += (long long)b * R * Cc;
    out += (long long)b * R * Cc;
    colsum += (long long)b * R;
    const int c0 = blockIdx.x * 32, r0 = blockIdx.y * 32;
    const int tx = threadIdx.x & 31, ty = threadIdx.x >> 5;
    #pragma unroll
    for (int rr = ty; rr < 32; rr += 8) {
        const float rs = 1.f / colsum[r0 + rr];
        tile[rr][tx] = f2bf(bf2f(in[(long long)(r0 + rr) * Cc + c0 + tx]) * rs);
    }
    __syncthreads();
    #pragma unroll
    for (int rr = ty; rr < 32; rr += 8)
        out[(long long)(c0 + rr) * R + r0 + tx] = tile[tx][rr];
}

extern "C" void kernel_launch(void* const* d_in, const int* in_sizes, int n_in,
                              void* d_out, int out_size, void* d_ws, size_t ws_size,
                              hipStream_t stream) {
    const float* q  = (const float*)d_in[0];
    const float* k  = (const float*)d_in[1];
    const float* v  = (const float*)d_in[2];
    const float* Wq = (const float*)d_in[3];
    const float* bq = (const float*)d_in[4];
    const float* Wk = (const float*)d_in[5];
    const float* bk = (const float*)d_in[6];
    const float* Wv = (const float*)d_in[7];
    const float* bv = (const float*)d_in[8];
    float* out = (float*)d_out;

    const int Bb = 8, L = 2048, D = 512;
    const long long BLD = (long long)Bb * L * D;   // 8,388,608
    const long long BLL = (long long)Bb * L * L;   // 33,554,432
    const long long DD  = (long long)D * D;

    // ---- workspace layout (shorts unless noted) ----
    short* base  = (short*)d_ws;
    short* q_bf  = base;                 // BLD
    short* k_bf  = q_bf  + BLD;         // BLD
    short* v_bf  = k_bf  + BLD;         // BLD
    short* qp_bf = v_bf  + BLD;         // BLD
    short* kp_bf = qp_bf + BLD;         // BLD
    short* vp_bf = kp_bf + BLD;         // BLD
    short* vpT   = vp_bf + BLD;         // BLD
    short* Wq_bf = vpT   + BLD;         // DD
    short* Wk_bf = Wq_bf + DD;          // DD
    short* Wv_bf = Wk_bf + DD;          // DD
    short* E_bf  = Wv_bf + DD;          // BLL shorts
    float* colsum = (float*)(E_bf + BLL); // B*L floats

    dim3 blk(256);

    // 1) fused casts + colsum zero (12736 blocks)
    prep<<<dim3(12736), blk, 0, stream>>>(q, k, v, Wq, Wk, Wv,
                                          q_bf, k_bf, v_bf,
                                          Wq_bf, Wk_bf, Wv_bf, colsum);

    // 2) fused projections: M=B*L=16384, N=D=512, K=D=512, out bf16
    dim3 gproj((Bb * L) / 128, D / 128, 3);
    proj_gemm<<<gproj, blk, 0, stream>>>(q_bf, k_bf, v_bf,
                                         Wq_bf, Wk_bf, Wv_bf,
                                         bq, bk, bv,
                                         qp_bf, kp_bf, vp_bf, D, D);

    // 3) E = exp2(qp @ kp^T), colsum[b,j] = sum_i E[b,i,j]   (M=N=L, K=D)
    dim3 gS(L / 128, L / 128, Bb);
    gemm_nt_exp_colsum<<<gS, blk, 0, stream>>>(qp_bf, kp_bf, E_bf, colsum,
                                               L, D,
                                               (long long)L * D, (long long)L * D,
                                               (long long)L * L);

    // 4) vpT[d][j] = vp[j][d] / colsum[j]  per batch
    dim3 gT(D / 32, L / 32, Bb);
    transpose_scale_bf16<<<gT, blk, 0, stream>>>(vp_bf, colsum, vpT, L, D);

    // 5) out = E @ vpT^T : M=L (128-tiles), N=D (64-tiles), K=L
    dim3 gO(L / 128, D / 64, Bb);
    pv_gemm<<<gO, blk, 0, stream>>>(E_bf, vpT, out, D, L,
                                    (long long)L * L, (long long)D * L,
                                    (long long)L * D);
}